// Round 1
// baseline (735.481 us; speedup 1.0000x reference)
//
#include <hip/hip_runtime.h>
#include <stdint.h>

typedef short bf16x8 __attribute__((ext_vector_type(8)));
typedef float f32x4 __attribute__((ext_vector_type(4)));

#define NB 65536
#define LR 0.0001f
#define GDSCALE (2.0f / 65536.0f)

__device__ __forceinline__ unsigned short f2bf(float f) {
  union { float f; unsigned u; } cv; cv.f = f;
  unsigned u = cv.u;
  return (unsigned short)((u + 0x7FFFu + ((u >> 16) & 1u)) >> 16);
}
__device__ __forceinline__ float bf2f(unsigned short s) {
  union { unsigned u; float f; } cv; cv.u = ((unsigned)s) << 16;
  return cv.f;
}
__device__ __forceinline__ float sigm(float x) { return 1.0f / (1.0f + __expf(-x)); }
__device__ __forceinline__ float tanh_(float x) {
  float e = __expf(2.0f * x);
  return 1.0f - 2.0f / (e + 1.0f);   // safe at both infinities
}

// ---- prep: Wcat bf16 = [W_ih | W_hh] (512 x 256), theta0 = ones(768) ----
__global__ __launch_bounds__(256) void k_prep(const float* __restrict__ W_ih,
                                              const float* __restrict__ W_hh,
                                              unsigned short* __restrict__ Wcat,
                                              float* __restrict__ theta0) {
  if (blockIdx.x < 512) {
    int id = blockIdx.x * 256 + threadIdx.x;   // 512*256 = 131072 elements
    int n = id >> 8, k = id & 255;
    float val = (k < 128) ? W_ih[n * 128 + k] : W_hh[n * 128 + (k - 128)];
    Wcat[id] = f2bf(val);
  } else {
    int t = threadIdx.x;
    theta0[t] = 1.0f; theta0[t + 256] = 1.0f; theta0[t + 512] = 1.0f;
  }
}

// ---- K1: fused LSTM gates. 4 waves/block, 16 batch-rows/wave, 64 rows/block.
// Writes gvT (768 x 65536, bf16), c_new (fp32, second half of d_out), v atomics.
__global__ __launch_bounds__(256) void k_gates(const float* __restrict__ x,
                                               const float* __restrict__ h,
                                               const float* __restrict__ c,
                                               const float* __restrict__ b_ih,
                                               const unsigned short* __restrict__ Wcat,
                                               unsigned short* __restrict__ gvT,
                                               float* __restrict__ v_acc,
                                               float* __restrict__ out_c) {
  __shared__ float g_lds[64];
  __shared__ unsigned short tile[96 * 68];   // [6 gates *16 cols][64 b + pad]
  const int tid = threadIdx.x;
  const int w = tid >> 6, lane = tid & 63;
  const int lr16 = lane & 15, lg4 = lane >> 4;
  const int b0 = blockIdx.x * 64;
  const int wrow0 = b0 + w * 16;

  if (tid < 64) g_lds[tid] = x[(size_t)(b0 + tid) * 129 + 128];  // guarantor col

  // A fragments: row = wrow0+lr16, k = kk*32 + lg4*8 + e  (k<128 -> x, else h)
  bf16x8 afrag[8];
  {
    const int arow = wrow0 + lr16;
    const float* xr = x + (size_t)arow * 129;
    const float* hr = h + (size_t)arow * 128;
    const int kb = lg4 * 8;
#pragma unroll
    for (int kk = 0; kk < 8; ++kk) {
      int k = kk * 32 + kb;
      bf16x8 a;
      if (k < 128) {
#pragma unroll
        for (int e = 0; e < 8; ++e) a[e] = (short)f2bf(xr[k + e]);
      } else {
#pragma unroll
        for (int e = 0; e < 8; ++e) a[e] = (short)f2bf(hr[k - 128 + e]);
      }
      afrag[kk] = a;
    }
  }
  __syncthreads();

  for (int jt = 0; jt < 8; ++jt) {
    const int j0 = jt * 16;
    const int col = j0 + lr16;                 // hidden unit index 0..127
    float bi0 = b_ih[col], bf0 = b_ih[128 + col], bc0 = b_ih[256 + col], bo0 = b_ih[384 + col];
    f32x4 zi = {bi0, bi0, bi0, bi0};
    f32x4 zf = {bf0, bf0, bf0, bf0};
    f32x4 zc = {bc0, bc0, bc0, bc0};
    f32x4 zo = {bo0, bo0, bo0, bo0};
#pragma unroll
    for (int kk = 0; kk < 8; ++kk) {
      const int koff = kk * 32 + lg4 * 8;
      const unsigned short* wp = Wcat + koff;
      bf16x8 wbi = *(const bf16x8*)(wp + (size_t)(0 * 128 + col) * 256);
      bf16x8 wbf = *(const bf16x8*)(wp + (size_t)(1 * 128 + col) * 256);
      bf16x8 wbc = *(const bf16x8*)(wp + (size_t)(2 * 128 + col) * 256);
      bf16x8 wbo = *(const bf16x8*)(wp + (size_t)(3 * 128 + col) * 256);
      zi = __builtin_amdgcn_mfma_f32_16x16x32_bf16(afrag[kk], wbi, zi, 0, 0, 0);
      zf = __builtin_amdgcn_mfma_f32_16x16x32_bf16(afrag[kk], wbf, zf, 0, 0, 0);
      zc = __builtin_amdgcn_mfma_f32_16x16x32_bf16(afrag[kk], wbc, zc, 0, 0, 0);
      zo = __builtin_amdgcn_mfma_f32_16x16x32_bf16(afrag[kk], wbo, zo, 0, 0, 0);
    }
    float pi = 0.f, pf = 0.f, pct = 0.f, pcn = 0.f, po = 0.f, ph = 0.f;
#pragma unroll
    for (int r = 0; r < 4; ++r) {
      int m = lg4 * 4 + r;                 // C/D layout: row=(lane>>4)*4+r, col=lane&15
      int brow = wrow0 + m;
      float gi = sigm(zi[r]);
      float gf = sigm(zf[r]);
      float gct = tanh_(zc[r]);
      float go = sigm(zo[r]);
      float cv = c[(size_t)brow * 128 + col];
      float cn = gf * cv + gi * gct;
      float ht = go * tanh_(cn);
      out_c[(size_t)brow * 128 + col] = cn;    // fp32 exact-path output
      float gg = g_lds[w * 16 + m];
      pi += gi * gg; pf += gf * gg; pct += gct * gg;
      pcn += cn * gg; po += go * gg; ph += ht * gg;
      int bb = w * 16 + m;
      tile[(0 * 16 + lr16) * 68 + bb] = f2bf(gi);
      tile[(1 * 16 + lr16) * 68 + bb] = f2bf(gf);
      tile[(2 * 16 + lr16) * 68 + bb] = f2bf(gct);
      tile[(3 * 16 + lr16) * 68 + bb] = f2bf(cn);
      tile[(4 * 16 + lr16) * 68 + bb] = f2bf(go);
      tile[(5 * 16 + lr16) * 68 + bb] = f2bf(ht);
    }
    // v partials: reduce across the 4 row-groups (lanes differing in bits 4,5)
    float p;
    p = pi;  p += __shfl_xor(p, 16); p += __shfl_xor(p, 32); if (lane < 16) atomicAdd(&v_acc[0 * 128 + col], p);
    p = pf;  p += __shfl_xor(p, 16); p += __shfl_xor(p, 32); if (lane < 16) atomicAdd(&v_acc[1 * 128 + col], p);
    p = pct; p += __shfl_xor(p, 16); p += __shfl_xor(p, 32); if (lane < 16) atomicAdd(&v_acc[2 * 128 + col], p);
    p = pcn; p += __shfl_xor(p, 16); p += __shfl_xor(p, 32); if (lane < 16) atomicAdd(&v_acc[3 * 128 + col], p);
    p = po;  p += __shfl_xor(p, 16); p += __shfl_xor(p, 32); if (lane < 16) atomicAdd(&v_acc[4 * 128 + col], p);
    p = ph;  p += __shfl_xor(p, 16); p += __shfl_xor(p, 32); if (lane < 16) atomicAdd(&v_acc[5 * 128 + col], p);
    __syncthreads();
    // cooperative coalesced store of the transposed tile: 96 gv-rows x 64 b's
#pragma unroll
    for (int pass = 0; pass < 12; ++pass) {
      int row = (tid >> 5) + pass * 8;       // 0..95
      int pr = tid & 31;                     // ushort2 pair index
      unsigned short u0 = tile[row * 68 + 2 * pr];
      unsigned short u1 = tile[row * 68 + 2 * pr + 1];
      int g = row >> 4, cc = row & 15;
      size_t grow = (size_t)(g * 128 + j0 + cc);
      unsigned val = (unsigned)u0 | ((unsigned)u1 << 16);
      *(unsigned*)(gvT + grow * (size_t)NB + b0 + 2 * pr) = val;
    }
    __syncthreads();
  }
}

// ---- K2: M = gvT * gvT^T  (768x768 fp32), split-K atomics, symmetric tiles ----
__global__ __launch_bounds__(256) void k_syrk(const unsigned short* __restrict__ gvT,
                                              float* __restrict__ M) {
  const int tid = threadIdx.x;
  const int w = tid >> 6, lane = tid & 63;
  const int lr16 = lane & 15, lg4 = lane >> 4;
  // unrank blockIdx.x in [0,21) -> (tj<=tk) tile pair of 128x128 tiles
  int r = blockIdx.x, tj = 0;
  while (r >= 6 - tj) { r -= 6 - tj; ++tj; }
  int tk = tj + r;
  const int j0 = tj * 128 + (w >> 1) * 64;
  const int k0 = tk * 128 + (w & 1) * 64;
  const size_t bbase = (size_t)blockIdx.y * 2048 + lg4 * 8;

  const unsigned short* pa[4];
  const unsigned short* pb[4];
#pragma unroll
  for (int i = 0; i < 4; ++i) {
    pa[i] = gvT + (size_t)(j0 + i * 16 + lr16) * NB + bbase;
    pb[i] = gvT + (size_t)(k0 + i * 16 + lr16) * NB + bbase;
  }
  f32x4 acc[4][4];
#pragma unroll
  for (int i = 0; i < 4; ++i)
#pragma unroll
    for (int j = 0; j < 4; ++j) acc[i][j] = (f32x4){0.f, 0.f, 0.f, 0.f};

  for (int s = 0; s < 64; ++s) {   // 64 steps * 32 b = 2048 b per chunk
    bf16x8 af[4], bfr[4];
#pragma unroll
    for (int i = 0; i < 4; ++i) { af[i] = *(const bf16x8*)pa[i]; bfr[i] = *(const bf16x8*)pb[i]; }
#pragma unroll
    for (int i = 0; i < 4; ++i)
#pragma unroll
      for (int j = 0; j < 4; ++j)
        acc[i][j] = __builtin_amdgcn_mfma_f32_16x16x32_bf16(af[i], bfr[j], acc[i][j], 0, 0, 0);
#pragma unroll
    for (int i = 0; i < 4; ++i) { pa[i] += 32; pb[i] += 32; }
  }
#pragma unroll
  for (int i = 0; i < 4; ++i)
#pragma unroll
    for (int j = 0; j < 4; ++j)
#pragma unroll
      for (int rr = 0; rr < 4; ++rr) {
        int Mr = j0 + i * 16 + lg4 * 4 + rr;
        int Mc = k0 + j * 16 + lr16;
        float val = acc[i][j][rr];
        atomicAdd(&M[(size_t)Mr * 768 + Mc], val);
        if (tj != tk) atomicAdd(&M[(size_t)Mc * 768 + Mr], val);
      }
}

// ---- GD step: theta_out = theta_in - LR * (2/B) * (M @ theta_in - v) ----
__global__ void k_gd(const float* __restrict__ M, const float* __restrict__ v,
                     const float* __restrict__ tin, float* __restrict__ tout) {
  const int row = blockIdx.x;       // 768 rows, 1 wave each
  const int lane = threadIdx.x;     // 64
  const float* Mr = M + (size_t)row * 768;
  float s = 0.f;
#pragma unroll
  for (int t = 0; t < 12; ++t) s += Mr[lane + t * 64] * tin[lane + t * 64];
  s += __shfl_xor(s, 32); s += __shfl_xor(s, 16); s += __shfl_xor(s, 8);
  s += __shfl_xor(s, 4);  s += __shfl_xor(s, 2);  s += __shfl_xor(s, 1);
  if (lane == 0) {
    float grad = GDSCALE * (s - v[row]);
    tout[row] = tin[row] - LR * grad;
  }
}

// ---- importance + argmax ----
__global__ void k_argmax(const float* __restrict__ theta, int* __restrict__ idx) {
  const int lane = threadIdx.x;   // 64
  float best = -1.f; int bi = 0;
#pragma unroll
  for (int g = 0; g < 6; ++g) {
    float s = fabsf(theta[g * 128 + lane]) + fabsf(theta[g * 128 + 64 + lane]);
    s += __shfl_xor(s, 32); s += __shfl_xor(s, 16); s += __shfl_xor(s, 8);
    s += __shfl_xor(s, 4);  s += __shfl_xor(s, 2);  s += __shfl_xor(s, 1);
    if (s > best) { best = s; bi = g; }   // uniform across lanes after reduce
  }
  if (lane == 0) *idx = bi;
}

// ---- gather selected candidate: out_h[b][j] = gvT[idx*128+j][b], via LDS transpose
__global__ __launch_bounds__(256) void k_gather(const unsigned short* __restrict__ gvT,
                                                const int* __restrict__ idxp,
                                                float* __restrict__ out) {
  __shared__ unsigned short tile[64 * 66];
  const int idx = *idxp;
  const int b0 = blockIdx.x * 64;
  const int j0 = blockIdx.y * 64;
  const int tid = threadIdx.x;
#pragma unroll
  for (int pass = 0; pass < 8; ++pass) {
    int rr = (tid >> 5) + pass * 8;   // 0..63 (j within tile)
    int pr = tid & 31;
    unsigned val = *(const unsigned*)(gvT + (size_t)(idx * 128 + j0 + rr) * NB + b0 + 2 * pr);
    tile[rr * 66 + 2 * pr] = (unsigned short)(val & 0xFFFFu);
    tile[rr * 66 + 2 * pr + 1] = (unsigned short)(val >> 16);
  }
  __syncthreads();
#pragma unroll
  for (int pass = 0; pass < 16; ++pass) {
    int jj = tid & 63;
    int bb = (tid >> 6) + 4 * pass;   // 0..63 (b within tile)
    out[(size_t)(b0 + bb) * 128 + j0 + jj] = bf2f(tile[jj * 66 + bb]);
  }
}

extern "C" void kernel_launch(void* const* d_in, const int* in_sizes, int n_in,
                              void* d_out, int out_size, void* d_ws, size_t ws_size,
                              hipStream_t stream) {
  const float* x = (const float*)d_in[0];
  const float* h = (const float*)d_in[1];
  const float* c = (const float*)d_in[2];
  const float* W_ih = (const float*)d_in[3];
  const float* b_ih = (const float*)d_in[4];
  const float* W_hh = (const float*)d_in[5];
  char* ws = (char*)d_ws;
  // ws layout (bytes):
  unsigned short* gvT = (unsigned short*)ws;                 // 768*65536*2 = 100,663,296
  unsigned short* Wcat = (unsigned short*)(ws + 100663296);  // 512*256*2   =     262,144
  float* M = (float*)(ws + 100925440);                       // 768*768*4   =   2,359,296
  float* v = (float*)(ws + 103284736);                       // 768*4       =       3,072
  float* theta = (float*)(ws + 103287808);                   // 2*768*4     =       6,144
  int* idx = (int*)(ws + 103293952);
  float* out_h = (float*)d_out;
  float* out_c = out_h + (size_t)NB * 128;

  hipMemsetAsync(M, 0, 2359296 + 3072, stream);              // zero M and v
  k_prep<<<513, 256, 0, stream>>>(W_ih, W_hh, Wcat, theta);
  k_gates<<<1024, 256, 0, stream>>>(x, h, c, b_ih, Wcat, gvT, v, out_c);
  k_syrk<<<dim3(21, 32), 256, 0, stream>>>(gvT, M);
  for (int s = 0; s < 13; ++s) {
    const float* tin = theta + (s & 1) * 768;
    float* tout = theta + ((s & 1) ^ 1) * 768;
    k_gd<<<768, 64, 0, stream>>>(M, v, tin, tout);
  }
  k_argmax<<<1, 64, 0, stream>>>(theta + 768, idx);          // 13 steps end in buffer 1
  k_gather<<<dim3(1024, 2), 256, 0, stream>>>(gvT, idx, out_h);
}

// Round 5
// 576.190 us; speedup vs baseline: 1.2765x; 1.2765x over previous
//
#include <hip/hip_runtime.h>
#include <stdint.h>

typedef short bf16x8 __attribute__((ext_vector_type(8)));
typedef float f32x4 __attribute__((ext_vector_type(4)));

#define NB 65536
#define NBP 65568              // padded leading stride (+64B/row) breaks L2 channel camping
#define LR 0.0001f
#define GDSCALE (2.0f / 65536.0f)

__device__ __forceinline__ unsigned short f2bf(float f) {
  union { float f; unsigned u; } cv; cv.f = f;
  unsigned u = cv.u;
  return (unsigned short)((u + 0x7FFFu + ((u >> 16) & 1u)) >> 16);
}
__device__ __forceinline__ float bf2f(unsigned short s) {
  union { unsigned u; float f; } cv; cv.u = ((unsigned)s) << 16;
  return cv.f;
}
__device__ __forceinline__ float sigm(float x) { return 1.0f / (1.0f + __expf(-x)); }
__device__ __forceinline__ float tanh_(float x) {
  float e = __expf(2.0f * x);
  return 1.0f - 2.0f / (e + 1.0f);   // safe at both infinities
}

// ---- prep: Wcat bf16 = [W_ih | W_hh] (512 x 256), theta0 = ones(768) ----
__global__ __launch_bounds__(256) void k_prep(const float* __restrict__ W_ih,
                                              const float* __restrict__ W_hh,
                                              unsigned short* __restrict__ Wcat,
                                              float* __restrict__ theta0) {
  if (blockIdx.x < 512) {
    int id = blockIdx.x * 256 + threadIdx.x;   // 512*256 = 131072 elements
    int n = id >> 8, k = id & 255;
    float val = (k < 128) ? W_ih[n * 128 + k] : W_hh[n * 128 + (k - 128)];
    Wcat[id] = f2bf(val);
  } else {
    int t = threadIdx.x;
    theta0[t] = 1.0f; theta0[t + 256] = 1.0f; theta0[t + 512] = 1.0f;
  }
}

// ---- K1: fused LSTM gates. 4 waves/block, 16 batch-rows/wave, 64 rows/block.
// Writes gvT (768 x NBP, bf16), c_new (fp32, second half of d_out), v atomics.
__global__ __launch_bounds__(256) void k_gates(const float* __restrict__ x,
                                               const float* __restrict__ h,
                                               const float* __restrict__ c,
                                               const float* __restrict__ b_ih,
                                               const unsigned short* __restrict__ Wcat,
                                               unsigned short* __restrict__ gvT,
                                               float* __restrict__ v_acc,
                                               float* __restrict__ out_c) {
  __shared__ float g_lds[64];
  __shared__ unsigned short tile[96 * 68];   // [6 gates *16 cols][64 b + pad]
  const int tid = threadIdx.x;
  const int w = tid >> 6, lane = tid & 63;
  const int lr16 = lane & 15, lg4 = lane >> 4;
  const int b0 = blockIdx.x * 64;
  const int wrow0 = b0 + w * 16;

  if (tid < 64) g_lds[tid] = x[(size_t)(b0 + tid) * 129 + 128];  // guarantor col

  // A fragments: row = wrow0+lr16, k = kk*32 + lg4*8 + e  (k<128 -> x, else h)
  bf16x8 afrag[8];
  {
    const int arow = wrow0 + lr16;
    const float* xr = x + (size_t)arow * 129;
    const float* hr = h + (size_t)arow * 128;
    const int kb = lg4 * 8;
#pragma unroll
    for (int kk = 0; kk < 8; ++kk) {
      int k = kk * 32 + kb;
      bf16x8 a;
      if (k < 128) {
#pragma unroll
        for (int e = 0; e < 8; ++e) a[e] = (short)f2bf(xr[k + e]);
      } else {
#pragma unroll
        for (int e = 0; e < 8; ++e) a[e] = (short)f2bf(hr[k - 128 + e]);
      }
      afrag[kk] = a;
    }
  }
  __syncthreads();

  for (int jt = 0; jt < 8; ++jt) {
    const int j0 = jt * 16;
    const int col = j0 + lr16;                 // hidden unit index 0..127
    float bi0 = b_ih[col], bf0 = b_ih[128 + col], bc0 = b_ih[256 + col], bo0 = b_ih[384 + col];
    f32x4 zi = {bi0, bi0, bi0, bi0};
    f32x4 zf = {bf0, bf0, bf0, bf0};
    f32x4 zc = {bc0, bc0, bc0, bc0};
    f32x4 zo = {bo0, bo0, bo0, bo0};
#pragma unroll
    for (int kk = 0; kk < 8; ++kk) {
      const int koff = kk * 32 + lg4 * 8;
      const unsigned short* wp = Wcat + koff;
      bf16x8 wbi = *(const bf16x8*)(wp + (size_t)(0 * 128 + col) * 256);
      bf16x8 wbf = *(const bf16x8*)(wp + (size_t)(1 * 128 + col) * 256);
      bf16x8 wbc = *(const bf16x8*)(wp + (size_t)(2 * 128 + col) * 256);
      bf16x8 wbo = *(const bf16x8*)(wp + (size_t)(3 * 128 + col) * 256);
      zi = __builtin_amdgcn_mfma_f32_16x16x32_bf16(afrag[kk], wbi, zi, 0, 0, 0);
      zf = __builtin_amdgcn_mfma_f32_16x16x32_bf16(afrag[kk], wbf, zf, 0, 0, 0);
      zc = __builtin_amdgcn_mfma_f32_16x16x32_bf16(afrag[kk], wbc, zc, 0, 0, 0);
      zo = __builtin_amdgcn_mfma_f32_16x16x32_bf16(afrag[kk], wbo, zo, 0, 0, 0);
    }
    float pi = 0.f, pf = 0.f, pct = 0.f, pcn = 0.f, po = 0.f, ph = 0.f;
#pragma unroll
    for (int r = 0; r < 4; ++r) {
      int m = lg4 * 4 + r;                 // C/D layout: row=(lane>>4)*4+r, col=lane&15
      int brow = wrow0 + m;
      float gi = sigm(zi[r]);
      float gf = sigm(zf[r]);
      float gct = tanh_(zc[r]);
      float go = sigm(zo[r]);
      float cv = c[(size_t)brow * 128 + col];
      float cn = gf * cv + gi * gct;
      float ht = go * tanh_(cn);
      out_c[(size_t)brow * 128 + col] = cn;    // fp32 exact-path output
      float gg = g_lds[w * 16 + m];
      pi += gi * gg; pf += gf * gg; pct += gct * gg;
      pcn += cn * gg; po += go * gg; ph += ht * gg;
      int bb = w * 16 + m;
      tile[(0 * 16 + lr16) * 68 + bb] = f2bf(gi);
      tile[(1 * 16 + lr16) * 68 + bb] = f2bf(gf);
      tile[(2 * 16 + lr16) * 68 + bb] = f2bf(gct);
      tile[(3 * 16 + lr16) * 68 + bb] = f2bf(cn);
      tile[(4 * 16 + lr16) * 68 + bb] = f2bf(go);
      tile[(5 * 16 + lr16) * 68 + bb] = f2bf(ht);
    }
    // v partials: reduce across the 4 row-groups (lanes differing in bits 4,5)
    float p;
    p = pi;  p += __shfl_xor(p, 16); p += __shfl_xor(p, 32); if (lane < 16) atomicAdd(&v_acc[0 * 128 + col], p);
    p = pf;  p += __shfl_xor(p, 16); p += __shfl_xor(p, 32); if (lane < 16) atomicAdd(&v_acc[1 * 128 + col], p);
    p = pct; p += __shfl_xor(p, 16); p += __shfl_xor(p, 32); if (lane < 16) atomicAdd(&v_acc[2 * 128 + col], p);
    p = pcn; p += __shfl_xor(p, 16); p += __shfl_xor(p, 32); if (lane < 16) atomicAdd(&v_acc[3 * 128 + col], p);
    p = po;  p += __shfl_xor(p, 16); p += __shfl_xor(p, 32); if (lane < 16) atomicAdd(&v_acc[4 * 128 + col], p);
    p = ph;  p += __shfl_xor(p, 16); p += __shfl_xor(p, 32); if (lane < 16) atomicAdd(&v_acc[5 * 128 + col], p);
    __syncthreads();
    // cooperative coalesced store of the transposed tile: 96 gv-rows x 64 b's
#pragma unroll
    for (int pass = 0; pass < 12; ++pass) {
      int row = (tid >> 5) + pass * 8;       // 0..95
      int pr = tid & 31;                     // ushort2 pair index
      unsigned short u0 = tile[row * 68 + 2 * pr];
      unsigned short u1 = tile[row * 68 + 2 * pr + 1];
      int g = row >> 4, cc = row & 15;
      size_t grow = (size_t)(g * 128 + j0 + cc);
      unsigned val = (unsigned)u0 | ((unsigned)u1 << 16);
      *(unsigned*)(gvT + grow * (size_t)NBP + b0 + 2 * pr) = val;
    }
    __syncthreads();
  }
}

// ---- K2: M = gvT * gvT^T (768x768 fp32), split-K atomics, upper-triangle only,
//      register double-buffered prefetch, y=64 K-splits for occupancy ----
__global__ __launch_bounds__(256) void k_syrk(const unsigned short* __restrict__ gvT,
                                              float* __restrict__ M) {
  const int tid = threadIdx.x;
  const int w = tid >> 6, lane = tid & 63;
  const int lr16 = lane & 15, lg4 = lane >> 4;
  // unrank blockIdx.x in [0,21) -> (tj<=tk) tile pair of 128x128 tiles
  int r = blockIdx.x, tj = 0;
  while (r >= 6 - tj) { r -= 6 - tj; ++tj; }
  int tk = tj + r;
  const int j0 = tj * 128 + (w >> 1) * 64;
  const int k0 = tk * 128 + (w & 1) * 64;
  const size_t bbase = (size_t)blockIdx.y * 1024 + lg4 * 8;   // 1024 b's per block

  const unsigned short* pa[4];
  const unsigned short* pb[4];
#pragma unroll
  for (int i = 0; i < 4; ++i) {
    pa[i] = gvT + (size_t)(j0 + i * 16 + lr16) * NBP + bbase;
    pb[i] = gvT + (size_t)(k0 + i * 16 + lr16) * NBP + bbase;
  }
  f32x4 acc[4][4];
#pragma unroll
  for (int i = 0; i < 4; ++i)
#pragma unroll
    for (int j = 0; j < 4; ++j) acc[i][j] = (f32x4){0.f, 0.f, 0.f, 0.f};

  bf16x8 a0[4], b0[4], a1[4], b1[4];
#pragma unroll
  for (int i = 0; i < 4; ++i) { a0[i] = *(const bf16x8*)(pa[i]); b0[i] = *(const bf16x8*)(pb[i]); }

  for (int s = 0; s < 32; s += 2) {   // 32 steps * 32 b = 1024 b per chunk
    // prefetch step s+1 while computing step s
#pragma unroll
    for (int i = 0; i < 4; ++i) {
      a1[i] = *(const bf16x8*)(pa[i] + (s + 1) * 32);
      b1[i] = *(const bf16x8*)(pb[i] + (s + 1) * 32);
    }
#pragma unroll
    for (int i = 0; i < 4; ++i)
#pragma unroll
      for (int j = 0; j < 4; ++j)
        acc[i][j] = __builtin_amdgcn_mfma_f32_16x16x32_bf16(a0[i], b0[j], acc[i][j], 0, 0, 0);
    // prefetch step s+2 (last iter overreads into row padding — never used)
#pragma unroll
    for (int i = 0; i < 4; ++i) {
      a0[i] = *(const bf16x8*)(pa[i] + (s + 2) * 32);
      b0[i] = *(const bf16x8*)(pb[i] + (s + 2) * 32);
    }
#pragma unroll
    for (int i = 0; i < 4; ++i)
#pragma unroll
      for (int j = 0; j < 4; ++j)
        acc[i][j] = __builtin_amdgcn_mfma_f32_16x16x32_bf16(a1[i], b1[j], acc[i][j], 0, 0, 0);
  }
#pragma unroll
  for (int i = 0; i < 4; ++i)
#pragma unroll
    for (int j = 0; j < 4; ++j)
#pragma unroll
      for (int rr = 0; rr < 4; ++rr) {
        int Mr = j0 + i * 16 + lg4 * 4 + rr;
        int Mc = k0 + j * 16 + lr16;
        atomicAdd(&M[(size_t)Mr * 768 + Mc], acc[i][j][rr]);   // upper triangle only
      }
}

// ---- symmetrize M (lower <- upper) after all syrk atomics complete ----
__global__ __launch_bounds__(256) void k_symm(float* __restrict__ M) {
  int row = blockIdx.y;
  int col = blockIdx.x * 256 + threadIdx.x;
  if (col > row) M[(size_t)col * 768 + row] = M[(size_t)row * 768 + col];
}

// ---- GD step: theta_out = theta_in - LR * (2/B) * (M @ theta_in - v) ----
__global__ void k_gd(const float* __restrict__ M, const float* __restrict__ v,
                     const float* __restrict__ tin, float* __restrict__ tout) {
  const int row = blockIdx.x;       // 768 rows, 1 wave each
  const int lane = threadIdx.x;     // 64
  const float* Mr = M + (size_t)row * 768;
  float s = 0.f;
#pragma unroll
  for (int t = 0; t < 12; ++t) s += Mr[lane + t * 64] * tin[lane + t * 64];
  s += __shfl_xor(s, 32); s += __shfl_xor(s, 16); s += __shfl_xor(s, 8);
  s += __shfl_xor(s, 4);  s += __shfl_xor(s, 2);  s += __shfl_xor(s, 1);
  if (lane == 0) {
    float grad = GDSCALE * (s - v[row]);
    tout[row] = tin[row] - LR * grad;
  }
}

// ---- importance + argmax ----
__global__ void k_argmax(const float* __restrict__ theta, int* __restrict__ idx) {
  const int lane = threadIdx.x;   // 64
  float best = -1.f; int bi = 0;
#pragma unroll
  for (int g = 0; g < 6; ++g) {
    float s = fabsf(theta[g * 128 + lane]) + fabsf(theta[g * 128 + 64 + lane]);
    s += __shfl_xor(s, 32); s += __shfl_xor(s, 16); s += __shfl_xor(s, 8);
    s += __shfl_xor(s, 4);  s += __shfl_xor(s, 2);  s += __shfl_xor(s, 1);
    if (s > best) { best = s; bi = g; }   // uniform across lanes after reduce
  }
  if (lane == 0) *idx = bi;
}

// ---- gather selected candidate: out_h[b][j] = gvT[idx*128+j][b], via LDS transpose
__global__ __launch_bounds__(256) void k_gather(const unsigned short* __restrict__ gvT,
                                                const int* __restrict__ idxp,
                                                float* __restrict__ out) {
  __shared__ unsigned short tile[64 * 66];
  const int idx = *idxp;
  const int b0 = blockIdx.x * 64;
  const int j0 = blockIdx.y * 64;
  const int tid = threadIdx.x;
#pragma unroll
  for (int pass = 0; pass < 8; ++pass) {
    int rr = (tid >> 5) + pass * 8;   // 0..63 (j within tile)
    int pr = tid & 31;
    unsigned val = *(const unsigned*)(gvT + (size_t)(idx * 128 + j0 + rr) * NBP + b0 + 2 * pr);
    tile[rr * 66 + 2 * pr] = (unsigned short)(val & 0xFFFFu);
    tile[rr * 66 + 2 * pr + 1] = (unsigned short)(val >> 16);
  }
  __syncthreads();
#pragma unroll
  for (int pass = 0; pass < 16; ++pass) {
    int jj = tid & 63;
    int bb = (tid >> 6) + 4 * pass;   // 0..63 (b within tile)
    out[(size_t)(b0 + bb) * 128 + j0 + jj] = bf2f(tile[jj * 66 + bb]);
  }
}

extern "C" void kernel_launch(void* const* d_in, const int* in_sizes, int n_in,
                              void* d_out, int out_size, void* d_ws, size_t ws_size,
                              hipStream_t stream) {
  const float* x = (const float*)d_in[0];
  const float* h = (const float*)d_in[1];
  const float* c = (const float*)d_in[2];
  const float* W_ih = (const float*)d_in[3];
  const float* b_ih = (const float*)d_in[4];
  const float* W_hh = (const float*)d_in[5];
  char* ws = (char*)d_ws;
  // ws layout (bytes):
  unsigned short* gvT = (unsigned short*)ws;                  // 768*65568*2 = 100,712,448
  unsigned short* Wcat = (unsigned short*)(ws + 100712448);   // 512*256*2   =     262,144
  float* M = (float*)(ws + 100974592);                        // 768*768*4   =   2,359,296
  float* v = (float*)(ws + 103333888);                        // 768*4       =       3,072
  float* theta = (float*)(ws + 103336960);                    // 2*768*4     =       6,144
  int* idx = (int*)(ws + 103343104);
  float* out_h = (float*)d_out;
  float* out_c = out_h + (size_t)NB * 128;

  hipMemsetAsync(M, 0, 2359296 + 3072, stream);               // zero M and v
  k_prep<<<513, 256, 0, stream>>>(W_ih, W_hh, Wcat, theta);
  k_gates<<<1024, 256, 0, stream>>>(x, h, c, b_ih, Wcat, gvT, v, out_c);
  k_syrk<<<dim3(21, 64), 256, 0, stream>>>(gvT, M);
  k_symm<<<dim3(3, 768), 256, 0, stream>>>(M);
  for (int s = 0; s < 13; ++s) {
    const float* tin = theta + (s & 1) * 768;
    float* tout = theta + ((s & 1) ^ 1) * 768;
    k_gd<<<768, 64, 0, stream>>>(M, v, tin, tout);
  }
  k_argmax<<<1, 64, 0, stream>>>(theta + 768, idx);           // 13 steps end in buffer 1
  k_gather<<<dim3(1024, 2), 256, 0, stream>>>(gvT, idx, out_h);
}

// Round 9
// 439.065 us; speedup vs baseline: 1.6751x; 1.3123x over previous
//
#include <hip/hip_runtime.h>
#include <stdint.h>

typedef short bf16x8 __attribute__((ext_vector_type(8)));
typedef float f32x4 __attribute__((ext_vector_type(4)));

#define NB 65536
#define NBP 65568              // padded leading stride (+64B/row) breaks L2 channel camping
#define LR 0.0001f
#define GDSCALE (2.0f / 65536.0f)

__device__ __forceinline__ unsigned short f2bf(float f) {
  union { float f; unsigned u; } cv; cv.f = f;
  unsigned u = cv.u;
  return (unsigned short)((u + 0x7FFFu + ((u >> 16) & 1u)) >> 16);
}
__device__ __forceinline__ float bf2f(unsigned short s) {
  union { unsigned u; float f; } cv; cv.u = ((unsigned)s) << 16;
  return cv.f;
}
__device__ __forceinline__ float sigm(float x) { return 1.0f / (1.0f + __expf(-x)); }
__device__ __forceinline__ float tanh_(float x) {
  float e = __expf(2.0f * x);
  return 1.0f - 2.0f / (e + 1.0f);   // safe at both infinities
}

// ---- prep: Wcat bf16 = [W_ih | W_hh] (512 x 256), theta0 = ones(768) ----
__global__ __launch_bounds__(256) void k_prep(const float* __restrict__ W_ih,
                                              const float* __restrict__ W_hh,
                                              unsigned short* __restrict__ Wcat,
                                              float* __restrict__ theta0) {
  if (blockIdx.x < 512) {
    int id = blockIdx.x * 256 + threadIdx.x;   // 512*256 = 131072 elements
    int n = id >> 8, k = id & 255;
    float val = (k < 128) ? W_ih[n * 128 + k] : W_hh[n * 128 + (k - 128)];
    Wcat[id] = f2bf(val);
  } else {
    int t = threadIdx.x;
    theta0[t] = 1.0f; theta0[t + 256] = 1.0f; theta0[t + 512] = 1.0f;
  }
}

// ---- K1: fused LSTM gates. 4 waves/block, 16 batch-rows/wave, 64 rows/block.
// Weights staged per-jt into LDS; v accumulated in LDS, one atomic pass at end.
__global__ __launch_bounds__(256) void k_gates(const float* __restrict__ x,
                                               const float* __restrict__ h,
                                               const float* __restrict__ c,
                                               const float* __restrict__ b_ih,
                                               const unsigned short* __restrict__ Wcat,
                                               unsigned short* __restrict__ gvT,
                                               float* __restrict__ v_acc,
                                               float* __restrict__ out_c) {
  __shared__ unsigned short wbuf[64 * 264];  // [4 gates x 16 cols][256 k + 8 pad] = 33.8 KB
  __shared__ unsigned short tile[96 * 72];   // [6 gates x 16 cols][64 b + pad], 16B-aligned rows
  __shared__ float vpart[768];
  __shared__ float g_lds[64];
  const int tid = threadIdx.x;
  const int w = tid >> 6, lane = tid & 63;
  const int lr16 = lane & 15, lg4 = lane >> 4;
  const int b0 = blockIdx.x * 64;
  const int wrow0 = b0 + w * 16;

  if (tid < 64) g_lds[tid] = x[(size_t)(b0 + tid) * 129 + 128];  // guarantor col
  vpart[tid] = 0.f; vpart[tid + 256] = 0.f; vpart[tid + 512] = 0.f;

  // A fragments: row = wrow0+lr16, k = kk*32 + lg4*8 + e  (k<128 -> x, else h)
  bf16x8 afrag[8];
  {
    const int arow = wrow0 + lr16;
    const float* xr = x + (size_t)arow * 129;
    const float* hr = h + (size_t)arow * 128;
    const int kb = lg4 * 8;
#pragma unroll
    for (int kk = 0; kk < 8; ++kk) {
      int k = kk * 32 + kb;
      bf16x8 a;
      if (k < 128) {
#pragma unroll
        for (int e = 0; e < 8; ++e) a[e] = (short)f2bf(xr[k + e]);
      } else {
#pragma unroll
        for (int e = 0; e < 8; ++e) a[e] = (short)f2bf(hr[k - 128 + e]);
      }
      afrag[kk] = a;
    }
  }

  // stage weights for col-tile jt: 64 rows (4 gates x 16 cols) x 256 k, coalesced
  auto stage = [&](int jt) {
    int row = tid >> 3, sub = tid & 7;       // 32 rows per pass, 64 B per thread
#pragma unroll
    for (int pass = 0; pass < 2; ++pass) {
      int rr = row + pass * 32;
      int g = rr >> 4, cc = rr & 15;
      const unsigned short* src = Wcat + (size_t)(g * 128 + jt * 16 + cc) * 256 + sub * 32;
      unsigned short* dst = wbuf + rr * 264 + sub * 32;
#pragma unroll
      for (int i = 0; i < 4; ++i)
        *(bf16x8*)(dst + i * 8) = *(const bf16x8*)(src + i * 8);
    }
  };

  stage(0);
  __syncthreads();

  for (int jt = 0; jt < 8; ++jt) {
    const int j0 = jt * 16;
    const int col = j0 + lr16;                 // hidden unit index 0..127
    float bi0 = b_ih[col], bf0 = b_ih[128 + col], bc0 = b_ih[256 + col], bo0 = b_ih[384 + col];
    f32x4 zi = {bi0, bi0, bi0, bi0};
    f32x4 zf = {bf0, bf0, bf0, bf0};
    f32x4 zc = {bc0, bc0, bc0, bc0};
    f32x4 zo = {bo0, bo0, bo0, bo0};
#pragma unroll
    for (int kk = 0; kk < 8; ++kk) {
      const unsigned short* wp = wbuf + kk * 32 + lg4 * 8;
      bf16x8 wbi = *(const bf16x8*)(wp + (0 * 16 + lr16) * 264);
      bf16x8 wbf = *(const bf16x8*)(wp + (1 * 16 + lr16) * 264);
      bf16x8 wbc = *(const bf16x8*)(wp + (2 * 16 + lr16) * 264);
      bf16x8 wbo = *(const bf16x8*)(wp + (3 * 16 + lr16) * 264);
      zi = __builtin_amdgcn_mfma_f32_16x16x32_bf16(afrag[kk], wbi, zi, 0, 0, 0);
      zf = __builtin_amdgcn_mfma_f32_16x16x32_bf16(afrag[kk], wbf, zf, 0, 0, 0);
      zc = __builtin_amdgcn_mfma_f32_16x16x32_bf16(afrag[kk], wbc, zc, 0, 0, 0);
      zo = __builtin_amdgcn_mfma_f32_16x16x32_bf16(afrag[kk], wbo, zo, 0, 0, 0);
    }
    float pi = 0.f, pf = 0.f, pct = 0.f, pcn = 0.f, po = 0.f, ph = 0.f;
#pragma unroll
    for (int r = 0; r < 4; ++r) {
      int m = lg4 * 4 + r;                 // C/D layout: row=(lane>>4)*4+r, col=lane&15
      int brow = wrow0 + m;
      float gi = sigm(zi[r]);
      float gf = sigm(zf[r]);
      float gct = tanh_(zc[r]);
      float go = sigm(zo[r]);
      float cv = c[(size_t)brow * 128 + col];
      float cn = gf * cv + gi * gct;
      float ht = go * tanh_(cn);
      out_c[(size_t)brow * 128 + col] = cn;    // fp32 exact-path output
      float gg = g_lds[w * 16 + m];
      pi += gi * gg; pf += gf * gg; pct += gct * gg;
      pcn += cn * gg; po += go * gg; ph += ht * gg;
      int bb = w * 16 + m;
      tile[(0 * 16 + lr16) * 72 + bb] = f2bf(gi);
      tile[(1 * 16 + lr16) * 72 + bb] = f2bf(gf);
      tile[(2 * 16 + lr16) * 72 + bb] = f2bf(gct);
      tile[(3 * 16 + lr16) * 72 + bb] = f2bf(cn);
      tile[(4 * 16 + lr16) * 72 + bb] = f2bf(go);
      tile[(5 * 16 + lr16) * 72 + bb] = f2bf(ht);
    }
    // v partials -> LDS (fast ds atomics; 4-way wave contention only)
    float p;
    p = pi;  p += __shfl_xor(p, 16); p += __shfl_xor(p, 32); if (lane < 16) atomicAdd(&vpart[0 * 128 + col], p);
    p = pf;  p += __shfl_xor(p, 16); p += __shfl_xor(p, 32); if (lane < 16) atomicAdd(&vpart[1 * 128 + col], p);
    p = pct; p += __shfl_xor(p, 16); p += __shfl_xor(p, 32); if (lane < 16) atomicAdd(&vpart[2 * 128 + col], p);
    p = pcn; p += __shfl_xor(p, 16); p += __shfl_xor(p, 32); if (lane < 16) atomicAdd(&vpart[3 * 128 + col], p);
    p = po;  p += __shfl_xor(p, 16); p += __shfl_xor(p, 32); if (lane < 16) atomicAdd(&vpart[4 * 128 + col], p);
    p = ph;  p += __shfl_xor(p, 16); p += __shfl_xor(p, 32); if (lane < 16) atomicAdd(&vpart[5 * 128 + col], p);
    __syncthreads();   // tile complete; wbuf reads complete
    // coalesced b128 store of transposed tile (96 rows x 128 B) + stage next weights
#pragma unroll
    for (int pass = 0; pass < 3; ++pass) {
      int row = (tid >> 3) + pass * 32;      // 0..95
      int seg = tid & 7;                     // 16 B segment within the 128 B row
      int g = row >> 4, cc = row & 15;
      size_t grow = (size_t)(g * 128 + j0 + cc);
      *(bf16x8*)(gvT + grow * (size_t)NBP + b0 + seg * 8) =
          *(const bf16x8*)(tile + row * 72 + seg * 8);
    }
    if (jt < 7) stage(jt + 1);
    __syncthreads();   // tile free to rewrite; wbuf staged for next jt
  }
  // one global atomic pass per block for v
  atomicAdd(&v_acc[tid],       vpart[tid]);
  atomicAdd(&v_acc[tid + 256], vpart[tid + 256]);
  atomicAdd(&v_acc[tid + 512], vpart[tid + 512]);
}

// ---- K2: M = gvT * gvT^T (768x768 fp32), split-K atomics, upper-triangle only,
//      register double-buffered prefetch, y=64 K-splits for occupancy ----
__global__ __launch_bounds__(256) void k_syrk(const unsigned short* __restrict__ gvT,
                                              float* __restrict__ M) {
  const int tid = threadIdx.x;
  const int w = tid >> 6, lane = tid & 63;
  const int lr16 = lane & 15, lg4 = lane >> 4;
  // unrank blockIdx.x in [0,21) -> (tj<=tk) tile pair of 128x128 tiles
  int r = blockIdx.x, tj = 0;
  while (r >= 6 - tj) { r -= 6 - tj; ++tj; }
  int tk = tj + r;
  const int j0 = tj * 128 + (w >> 1) * 64;
  const int k0 = tk * 128 + (w & 1) * 64;
  const size_t bbase = (size_t)blockIdx.y * 1024 + lg4 * 8;   // 1024 b's per block

  const unsigned short* pa[4];
  const unsigned short* pb[4];
#pragma unroll
  for (int i = 0; i < 4; ++i) {
    pa[i] = gvT + (size_t)(j0 + i * 16 + lr16) * NBP + bbase;
    pb[i] = gvT + (size_t)(k0 + i * 16 + lr16) * NBP + bbase;
  }
  f32x4 acc[4][4];
#pragma unroll
  for (int i = 0; i < 4; ++i)
#pragma unroll
    for (int j = 0; j < 4; ++j) acc[i][j] = (f32x4){0.f, 0.f, 0.f, 0.f};

  bf16x8 a0[4], b0[4], a1[4], b1[4];
#pragma unroll
  for (int i = 0; i < 4; ++i) { a0[i] = *(const bf16x8*)(pa[i]); b0[i] = *(const bf16x8*)(pb[i]); }

  for (int s = 0; s < 32; s += 2) {   // 32 steps * 32 b = 1024 b per chunk
    // prefetch step s+1 while computing step s
#pragma unroll
    for (int i = 0; i < 4; ++i) {
      a1[i] = *(const bf16x8*)(pa[i] + (s + 1) * 32);
      b1[i] = *(const bf16x8*)(pb[i] + (s + 1) * 32);
    }
#pragma unroll
    for (int i = 0; i < 4; ++i)
#pragma unroll
      for (int j = 0; j < 4; ++j)
        acc[i][j] = __builtin_amdgcn_mfma_f32_16x16x32_bf16(a0[i], b0[j], acc[i][j], 0, 0, 0);
    // prefetch step s+2 (last iter overreads into row padding — never used)
#pragma unroll
    for (int i = 0; i < 4; ++i) {
      a0[i] = *(const bf16x8*)(pa[i] + (s + 2) * 32);
      b0[i] = *(const bf16x8*)(pb[i] + (s + 2) * 32);
    }
#pragma unroll
    for (int i = 0; i < 4; ++i)
#pragma unroll
      for (int j = 0; j < 4; ++j)
        acc[i][j] = __builtin_amdgcn_mfma_f32_16x16x32_bf16(a1[i], b1[j], acc[i][j], 0, 0, 0);
  }
#pragma unroll
  for (int i = 0; i < 4; ++i)
#pragma unroll
    for (int j = 0; j < 4; ++j)
#pragma unroll
      for (int rr = 0; rr < 4; ++rr) {
        int Mr = j0 + i * 16 + lg4 * 4 + rr;
        int Mc = k0 + j * 16 + lr16;
        atomicAdd(&M[(size_t)Mr * 768 + Mc], acc[i][j][rr]);   // upper triangle only
      }
}

// ---- symmetrize M (lower <- upper) after all syrk atomics complete ----
__global__ __launch_bounds__(256) void k_symm(float* __restrict__ M) {
  int row = blockIdx.y;
  int col = blockIdx.x * 256 + threadIdx.x;
  if (col > row) M[(size_t)col * 768 + row] = M[(size_t)row * 768 + col];
}

// ---- GD step: theta_out = theta_in - LR * (2/B) * (M @ theta_in - v) ----
__global__ void k_gd(const float* __restrict__ M, const float* __restrict__ v,
                     const float* __restrict__ tin, float* __restrict__ tout) {
  const int row = blockIdx.x;       // 768 rows, 1 wave each
  const int lane = threadIdx.x;     // 64
  const float* Mr = M + (size_t)row * 768;
  float s = 0.f;
#pragma unroll
  for (int t = 0; t < 12; ++t) s += Mr[lane + t * 64] * tin[lane + t * 64];
  s += __shfl_xor(s, 32); s += __shfl_xor(s, 16); s += __shfl_xor(s, 8);
  s += __shfl_xor(s, 4);  s += __shfl_xor(s, 2);  s += __shfl_xor(s, 1);
  if (lane == 0) {
    float grad = GDSCALE * (s - v[row]);
    tout[row] = tin[row] - LR * grad;
  }
}

// ---- importance + argmax ----
__global__ void k_argmax(const float* __restrict__ theta, int* __restrict__ idx) {
  const int lane = threadIdx.x;   // 64
  float best = -1.f; int bi = 0;
#pragma unroll
  for (int g = 0; g < 6; ++g) {
    float s = fabsf(theta[g * 128 + lane]) + fabsf(theta[g * 128 + 64 + lane]);
    s += __shfl_xor(s, 32); s += __shfl_xor(s, 16); s += __shfl_xor(s, 8);
    s += __shfl_xor(s, 4);  s += __shfl_xor(s, 2);  s += __shfl_xor(s, 1);
    if (s > best) { best = s; bi = g; }   // uniform across lanes after reduce
  }
  if (lane == 0) *idx = bi;
}

// ---- gather selected candidate: out_h[b][j] = gvT[idx*128+j][b], via LDS transpose
__global__ __launch_bounds__(256) void k_gather(const unsigned short* __restrict__ gvT,
                                                const int* __restrict__ idxp,
                                                float* __restrict__ out) {
  __shared__ unsigned short tile[64 * 66];
  const int idx = *idxp;
  const int b0 = blockIdx.x * 64;
  const int j0 = blockIdx.y * 64;
  const int tid = threadIdx.x;
#pragma unroll
  for (int pass = 0; pass < 8; ++pass) {
    int rr = (tid >> 5) + pass * 8;   // 0..63 (j within tile)
    int pr = tid & 31;
    unsigned val = *(const unsigned*)(gvT + (size_t)(idx * 128 + j0 + rr) * NBP + b0 + 2 * pr);
    tile[rr * 66 + 2 * pr] = (unsigned short)(val & 0xFFFFu);
    tile[rr * 66 + 2 * pr + 1] = (unsigned short)(val >> 16);
  }
  __syncthreads();
#pragma unroll
  for (int pass = 0; pass < 16; ++pass) {
    int jj = tid & 63;
    int bb = (tid >> 6) + 4 * pass;   // 0..63 (b within tile)
    out[(size_t)(b0 + bb) * 128 + j0 + jj] = bf2f(tile[jj * 66 + bb]);
  }
}

extern "C" void kernel_launch(void* const* d_in, const int* in_sizes, int n_in,
                              void* d_out, int out_size, void* d_ws, size_t ws_size,
                              hipStream_t stream) {
  const float* x = (const float*)d_in[0];
  const float* h = (const float*)d_in[1];
  const float* c = (const float*)d_in[2];
  const float* W_ih = (const float*)d_in[3];
  const float* b_ih = (const float*)d_in[4];
  const float* W_hh = (const float*)d_in[5];
  char* ws = (char*)d_ws;
  // ws layout (bytes):
  unsigned short* gvT = (unsigned short*)ws;                  // 768*65568*2 = 100,712,448
  unsigned short* Wcat = (unsigned short*)(ws + 100712448);   // 512*256*2   =     262,144
  float* M = (float*)(ws + 100974592);                        // 768*768*4   =   2,359,296
  float* v = (float*)(ws + 103333888);                        // 768*4       =       3,072
  float* theta = (float*)(ws + 103336960);                    // 2*768*4     =       6,144
  int* idx = (int*)(ws + 103343104);
  float* out_h = (float*)d_out;
  float* out_c = out_h + (size_t)NB * 128;

  hipMemsetAsync(M, 0, 2359296 + 3072, stream);               // zero M and v
  k_prep<<<513, 256, 0, stream>>>(W_ih, W_hh, Wcat, theta);
  k_gates<<<1024, 256, 0, stream>>>(x, h, c, b_ih, Wcat, gvT, v, out_c);
  k_syrk<<<dim3(21, 64), 256, 0, stream>>>(gvT, M);
  k_symm<<<dim3(3, 768), 256, 0, stream>>>(M);
  for (int s = 0; s < 13; ++s) {
    const float* tin = theta + (s & 1) * 768;
    float* tout = theta + ((s & 1) ^ 1) * 768;
    k_gd<<<768, 64, 0, stream>>>(M, v, tin, tout);
  }
  k_argmax<<<1, 64, 0, stream>>>(theta + 768, idx);           // 13 steps end in buffer 1
  k_gather<<<dim3(1024, 2), 256, 0, stream>>>(gvT, idx, out_h);
}

// Round 10
// 418.840 us; speedup vs baseline: 1.7560x; 1.0483x over previous
//
#include <hip/hip_runtime.h>
#include <stdint.h>

typedef short bf16x8 __attribute__((ext_vector_type(8)));
typedef float f32x4 __attribute__((ext_vector_type(4)));

#define NB 65536
#define NBP8 65600             // fp8 row stride in bytes (+64B pad breaks L2 channel camping)
#define LR 0.0001f
#define GDSCALE (2.0f / 65536.0f)

__device__ __forceinline__ unsigned short f2bf(float f) {
  union { float f; unsigned u; } cv; cv.f = f;
  unsigned u = cv.u;
  return (unsigned short)((u + 0x7FFFu + ((u >> 16) & 1u)) >> 16);
}
__device__ __forceinline__ float bf2f(unsigned short s) {
  union { unsigned u; float f; } cv; cv.u = ((unsigned)s) << 16;
  return cv.f;
}
// float -> OCP e4m3fn, RNE; flushes |x|<2^-10-ish via rint; clamps to 448
__device__ __forceinline__ unsigned char f2e4m3(float f) {
  union { float f; unsigned u; } cv; cv.f = f;
  unsigned u = cv.u;
  unsigned char sign = (unsigned char)((u >> 24) & 0x80);
  int exp = (int)((u >> 23) & 0xFF) - 127;
  unsigned man = u & 0x7FFFFF;
  if (exp >= -6) {
    if (exp > 8) return sign | 0x7E;
    unsigned full = ((unsigned)(exp + 7) << 3) | (man >> 20);
    unsigned rem = man & 0xFFFFF;
    if (rem > 0x80000u || (rem == 0x80000u && (full & 1u))) full++;
    if (full >= 0x7Fu) full = 0x7Eu;
    return sign | (unsigned char)full;
  }
  int q = (int)rintf(fabsf(f) * 512.0f);   // subnormal path: units of 2^-9 (q<=8 rolls into 2^-6)
  return sign | (unsigned char)q;
}
__device__ __forceinline__ float e4m32f(unsigned char b) {
  unsigned em = b & 0x7Fu;
  float mag;
  if (em < 8u) {
    mag = (float)em * (1.0f / 512.0f);
  } else {
    union { unsigned u; float f; } cv;
    cv.u = (((em >> 3) + 120u) << 23) | ((em & 7u) << 20);
    mag = cv.f;
  }
  return (b & 0x80u) ? -mag : mag;
}
__device__ __forceinline__ float sigm(float x) { return 1.0f / (1.0f + __expf(-x)); }
__device__ __forceinline__ float tanh_(float x) {
  float e = __expf(2.0f * x);
  return 1.0f - 2.0f / (e + 1.0f);   // safe at both infinities
}

// ---- prep: Wcat bf16 = [W_ih | W_hh] (512 x 256), theta0 = ones(768) ----
__global__ __launch_bounds__(256) void k_prep(const float* __restrict__ W_ih,
                                              const float* __restrict__ W_hh,
                                              unsigned short* __restrict__ Wcat,
                                              float* __restrict__ theta0) {
  if (blockIdx.x < 512) {
    int id = blockIdx.x * 256 + threadIdx.x;
    int n = id >> 8, k = id & 255;
    float val = (k < 128) ? W_ih[n * 128 + k] : W_hh[n * 128 + (k - 128)];
    Wcat[id] = f2bf(val);
  } else {
    int t = threadIdx.x;
    theta0[t] = 1.0f; theta0[t + 256] = 1.0f; theta0[t + 512] = 1.0f;
  }
}

// ---- K1: fused LSTM gates. Writes gvT8 (768 x NBP8 fp8), c_new fp32, v via LDS.
__global__ __launch_bounds__(256) void k_gates(const float* __restrict__ x,
                                               const float* __restrict__ h,
                                               const float* __restrict__ c,
                                               const float* __restrict__ b_ih,
                                               const unsigned short* __restrict__ Wcat,
                                               unsigned char* __restrict__ gvT8,
                                               float* __restrict__ v_acc,
                                               float* __restrict__ out_c) {
  __shared__ unsigned short wbuf[64 * 264];  // [4 gates x 16 cols][256 k + 8 pad]
  __shared__ unsigned short tile[96 * 72];   // [6 gates x 16 cols][64 b + pad]
  __shared__ float vpart[768];
  __shared__ float g_lds[64];
  const int tid = threadIdx.x;
  const int w = tid >> 6, lane = tid & 63;
  const int lr16 = lane & 15, lg4 = lane >> 4;
  const int b0 = blockIdx.x * 64;
  const int wrow0 = b0 + w * 16;

  if (tid < 64) g_lds[tid] = x[(size_t)(b0 + tid) * 129 + 128];  // guarantor col
  vpart[tid] = 0.f; vpart[tid + 256] = 0.f; vpart[tid + 512] = 0.f;

  bf16x8 afrag[8];
  {
    const int arow = wrow0 + lr16;
    const float* xr = x + (size_t)arow * 129;
    const float* hr = h + (size_t)arow * 128;
    const int kb = lg4 * 8;
#pragma unroll
    for (int kk = 0; kk < 8; ++kk) {
      int k = kk * 32 + kb;
      bf16x8 a;
      if (k < 128) {
#pragma unroll
        for (int e = 0; e < 8; ++e) a[e] = (short)f2bf(xr[k + e]);
      } else {
#pragma unroll
        for (int e = 0; e < 8; ++e) a[e] = (short)f2bf(hr[k - 128 + e]);
      }
      afrag[kk] = a;
    }
  }

  auto stage = [&](int jt) {
    int row = tid >> 3, sub = tid & 7;
#pragma unroll
    for (int pass = 0; pass < 2; ++pass) {
      int rr = row + pass * 32;
      int g = rr >> 4, cc = rr & 15;
      const unsigned short* src = Wcat + (size_t)(g * 128 + jt * 16 + cc) * 256 + sub * 32;
      unsigned short* dst = wbuf + rr * 264 + sub * 32;
#pragma unroll
      for (int i = 0; i < 4; ++i)
        *(bf16x8*)(dst + i * 8) = *(const bf16x8*)(src + i * 8);
    }
  };

  stage(0);
  __syncthreads();

  for (int jt = 0; jt < 8; ++jt) {
    const int j0 = jt * 16;
    const int col = j0 + lr16;
    float bi0 = b_ih[col], bf0 = b_ih[128 + col], bc0 = b_ih[256 + col], bo0 = b_ih[384 + col];
    f32x4 zi = {bi0, bi0, bi0, bi0};
    f32x4 zf = {bf0, bf0, bf0, bf0};
    f32x4 zc = {bc0, bc0, bc0, bc0};
    f32x4 zo = {bo0, bo0, bo0, bo0};
#pragma unroll
    for (int kk = 0; kk < 8; ++kk) {
      const unsigned short* wp = wbuf + kk * 32 + lg4 * 8;
      bf16x8 wbi = *(const bf16x8*)(wp + (0 * 16 + lr16) * 264);
      bf16x8 wbf = *(const bf16x8*)(wp + (1 * 16 + lr16) * 264);
      bf16x8 wbc = *(const bf16x8*)(wp + (2 * 16 + lr16) * 264);
      bf16x8 wbo = *(const bf16x8*)(wp + (3 * 16 + lr16) * 264);
      zi = __builtin_amdgcn_mfma_f32_16x16x32_bf16(afrag[kk], wbi, zi, 0, 0, 0);
      zf = __builtin_amdgcn_mfma_f32_16x16x32_bf16(afrag[kk], wbf, zf, 0, 0, 0);
      zc = __builtin_amdgcn_mfma_f32_16x16x32_bf16(afrag[kk], wbc, zc, 0, 0, 0);
      zo = __builtin_amdgcn_mfma_f32_16x16x32_bf16(afrag[kk], wbo, zo, 0, 0, 0);
    }
    float pi = 0.f, pf = 0.f, pct = 0.f, pcn = 0.f, po = 0.f, ph = 0.f;
#pragma unroll
    for (int r = 0; r < 4; ++r) {
      int m = lg4 * 4 + r;                 // C/D: row=(lane>>4)*4+r, col=lane&15
      int brow = wrow0 + m;
      float gi = sigm(zi[r]);
      float gf = sigm(zf[r]);
      float gct = tanh_(zc[r]);
      float go = sigm(zo[r]);
      float cv = c[(size_t)brow * 128 + col];
      float cn = gf * cv + gi * gct;
      float ht = go * tanh_(cn);
      out_c[(size_t)brow * 128 + col] = cn;    // fp32 exact-path output (also gather src for idx==3)
      float gg = g_lds[w * 16 + m];
      pi += gi * gg; pf += gf * gg; pct += gct * gg;
      pcn += cn * gg; po += go * gg; ph += ht * gg;
      int bb = w * 16 + m;
      tile[(0 * 16 + lr16) * 72 + bb] = f2bf(gi);
      tile[(1 * 16 + lr16) * 72 + bb] = f2bf(gf);
      tile[(2 * 16 + lr16) * 72 + bb] = f2bf(gct);
      tile[(3 * 16 + lr16) * 72 + bb] = f2bf(cn);
      tile[(4 * 16 + lr16) * 72 + bb] = f2bf(go);
      tile[(5 * 16 + lr16) * 72 + bb] = f2bf(ht);
    }
    float p;
    p = pi;  p += __shfl_xor(p, 16); p += __shfl_xor(p, 32); if (lane < 16) atomicAdd(&vpart[0 * 128 + col], p);
    p = pf;  p += __shfl_xor(p, 16); p += __shfl_xor(p, 32); if (lane < 16) atomicAdd(&vpart[1 * 128 + col], p);
    p = pct; p += __shfl_xor(p, 16); p += __shfl_xor(p, 32); if (lane < 16) atomicAdd(&vpart[2 * 128 + col], p);
    p = pcn; p += __shfl_xor(p, 16); p += __shfl_xor(p, 32); if (lane < 16) atomicAdd(&vpart[3 * 128 + col], p);
    p = po;  p += __shfl_xor(p, 16); p += __shfl_xor(p, 32); if (lane < 16) atomicAdd(&vpart[4 * 128 + col], p);
    p = ph;  p += __shfl_xor(p, 16); p += __shfl_xor(p, 32); if (lane < 16) atomicAdd(&vpart[5 * 128 + col], p);
    __syncthreads();
    // fp8 store of transposed tile: 96 rows x 64 B, b64 per thread, 3 passes
#pragma unroll
    for (int pass = 0; pass < 3; ++pass) {
      int row = (tid >> 3) + pass * 32;
      int seg = tid & 7;
      int g = row >> 4, cc = row & 15;
      size_t grow = (size_t)(g * 128 + j0 + cc);
      bf16x8 vsrc = *(const bf16x8*)(tile + row * 72 + seg * 8);
      unsigned long long packed = 0;
#pragma unroll
      for (int e = 0; e < 8; ++e)
        packed |= (unsigned long long)f2e4m3(bf2f((unsigned short)vsrc[e])) << (8 * e);
      *(unsigned long long*)(gvT8 + grow * (size_t)NBP8 + b0 + seg * 8) = packed;
    }
    if (jt < 7) stage(jt + 1);
    __syncthreads();
  }
  atomicAdd(&v_acc[tid],       vpart[tid]);
  atomicAdd(&v_acc[tid + 256], vpart[tid + 256]);
  atomicAdd(&v_acc[tid + 512], vpart[tid + 512]);
}

// ---- K2: M = G G^T in fp8, upper-triangle atomics, K-chunk 2048, XCD-swizzled ----
__global__ __launch_bounds__(256) void k_syrk(const unsigned char* __restrict__ gvT8,
                                              float* __restrict__ M) {
  const int tid = threadIdx.x;
  const int w = tid >> 6, lane = tid & 63;
  const int lr16 = lane & 15, lg4 = lane >> 4;
  // bijective XCD swizzle: 672 blocks = 8 XCDs x 84; same-K-strip blocks share an XCD L2
  int p = blockIdx.x;
  int L = (p & 7) * 84 + (p >> 3);
  int r = L % 21, ychunk = L / 21;          // 21 tile-pairs, 32 K-chunks of 2048
  int tj = 0;
  while (r >= 6 - tj) { r -= 6 - tj; ++tj; }
  int tk = tj + r;
  const int j0 = tj * 128 + (w >> 1) * 64;
  const int k0 = tk * 128 + (w & 1) * 64;
  const size_t bbase = (size_t)ychunk * 2048 + lg4 * 8;

  const unsigned char* pa[4];
  const unsigned char* pb[4];
#pragma unroll
  for (int i = 0; i < 4; ++i) {
    pa[i] = gvT8 + (size_t)(j0 + i * 16 + lr16) * NBP8 + bbase;
    pb[i] = gvT8 + (size_t)(k0 + i * 16 + lr16) * NBP8 + bbase;
  }
  f32x4 acc[4][4];
#pragma unroll
  for (int i = 0; i < 4; ++i)
#pragma unroll
    for (int j = 0; j < 4; ++j) acc[i][j] = (f32x4){0.f, 0.f, 0.f, 0.f};

  long long a0[4], b0v[4], a1[4], b1v[4];
#pragma unroll
  for (int i = 0; i < 4; ++i) {
    a0[i] = *(const long long*)pa[i];
    b0v[i] = *(const long long*)pb[i];
  }
  for (int s = 0; s < 64; s += 2) {   // 64 steps * 32 b (bytes) = 2048 per chunk
#pragma unroll
    for (int i = 0; i < 4; ++i) {
      a1[i] = *(const long long*)(pa[i] + (s + 1) * 32);
      b1v[i] = *(const long long*)(pb[i] + (s + 1) * 32);
    }
#pragma unroll
    for (int i = 0; i < 4; ++i)
#pragma unroll
      for (int j = 0; j < 4; ++j)
        acc[i][j] = __builtin_amdgcn_mfma_f32_16x16x32_fp8_fp8(a0[i], b0v[j], acc[i][j], 0, 0, 0);
#pragma unroll
    for (int i = 0; i < 4; ++i) {   // last iter overreads into row padding — never used
      a0[i] = *(const long long*)(pa[i] + (s + 2) * 32);
      b0v[i] = *(const long long*)(pb[i] + (s + 2) * 32);
    }
#pragma unroll
    for (int i = 0; i < 4; ++i)
#pragma unroll
      for (int j = 0; j < 4; ++j)
        acc[i][j] = __builtin_amdgcn_mfma_f32_16x16x32_fp8_fp8(a1[i], b1v[j], acc[i][j], 0, 0, 0);
  }
#pragma unroll
  for (int i = 0; i < 4; ++i)
#pragma unroll
    for (int j = 0; j < 4; ++j)
#pragma unroll
      for (int rr = 0; rr < 4; ++rr) {
        int Mr = j0 + i * 16 + lg4 * 4 + rr;
        int Mc = k0 + j * 16 + lr16;
        atomicAdd(&M[(size_t)Mr * 768 + Mc], acc[i][j][rr]);
      }
}

// ---- symmetrize M (lower <- upper) ----
__global__ __launch_bounds__(256) void k_symm(float* __restrict__ M) {
  int row = blockIdx.y;
  int col = blockIdx.x * 256 + threadIdx.x;
  if (col > row) M[(size_t)col * 768 + row] = M[(size_t)row * 768 + col];
}

// ---- GD step ----
__global__ void k_gd(const float* __restrict__ M, const float* __restrict__ v,
                     const float* __restrict__ tin, float* __restrict__ tout) {
  const int row = blockIdx.x;
  const int lane = threadIdx.x;
  const float* Mr = M + (size_t)row * 768;
  float s = 0.f;
#pragma unroll
  for (int t = 0; t < 12; ++t) s += Mr[lane + t * 64] * tin[lane + t * 64];
  s += __shfl_xor(s, 32); s += __shfl_xor(s, 16); s += __shfl_xor(s, 8);
  s += __shfl_xor(s, 4);  s += __shfl_xor(s, 2);  s += __shfl_xor(s, 1);
  if (lane == 0) {
    float grad = GDSCALE * (s - v[row]);
    tout[row] = tin[row] - LR * grad;
  }
}

// ---- importance + argmax ----
__global__ void k_argmax(const float* __restrict__ theta, int* __restrict__ idx) {
  const int lane = threadIdx.x;
  float best = -1.f; int bi = 0;
#pragma unroll
  for (int g = 0; g < 6; ++g) {
    float s = fabsf(theta[g * 128 + lane]) + fabsf(theta[g * 128 + 64 + lane]);
    s += __shfl_xor(s, 32); s += __shfl_xor(s, 16); s += __shfl_xor(s, 8);
    s += __shfl_xor(s, 4);  s += __shfl_xor(s, 2);  s += __shfl_xor(s, 1);
    if (s > best) { best = s; bi = g; }
  }
  if (lane == 0) *idx = bi;
}

// ---- gather: idx==3 -> exact fp32 copy from out_c; else fp8 transpose read ----
__global__ __launch_bounds__(256) void k_gather(const unsigned char* __restrict__ gvT8,
                                                const float* __restrict__ src_c,
                                                const int* __restrict__ idxp,
                                                float* __restrict__ out) {
  __shared__ unsigned char tile[64 * 72];
  const int idx = *idxp;
  const int b0 = blockIdx.x * 64;
  const int j0 = blockIdx.y * 64;
  const int tid = threadIdx.x;
  if (idx == 3) {
    // c_new selected: its exact fp32 values are already in src_c (row-major [b][j])
#pragma unroll
    for (int pass = 0; pass < 4; ++pass) {
      int rr = (tid >> 4) + pass * 16;
      int sg = tid & 15;
      *(f32x4*)(out + (size_t)(b0 + rr) * 128 + j0 + sg * 4) =
          *(const f32x4*)(src_c + (size_t)(b0 + rr) * 128 + j0 + sg * 4);
    }
  } else {
#pragma unroll
    for (int pass = 0; pass < 2; ++pass) {
      int rr = (tid >> 3) + pass * 32;   // j within tile
      int seg = tid & 7;
      *(unsigned long long*)(tile + rr * 72 + seg * 8) =
          *(const unsigned long long*)(gvT8 + (size_t)(idx * 128 + j0 + rr) * NBP8 + b0 + seg * 8);
    }
    __syncthreads();
#pragma unroll
    for (int pass = 0; pass < 16; ++pass) {
      int jj = tid & 63;
      int bb = (tid >> 6) + 4 * pass;
      out[(size_t)(b0 + bb) * 128 + j0 + jj] = e4m32f(tile[jj * 72 + bb]);
    }
  }
}

extern "C" void kernel_launch(void* const* d_in, const int* in_sizes, int n_in,
                              void* d_out, int out_size, void* d_ws, size_t ws_size,
                              hipStream_t stream) {
  const float* x = (const float*)d_in[0];
  const float* h = (const float*)d_in[1];
  const float* c = (const float*)d_in[2];
  const float* W_ih = (const float*)d_in[3];
  const float* b_ih = (const float*)d_in[4];
  const float* W_hh = (const float*)d_in[5];
  char* ws = (char*)d_ws;
  // ws layout (bytes):
  unsigned char* gvT8 = (unsigned char*)ws;                  // 768*65600   = 50,380,800
  unsigned short* Wcat = (unsigned short*)(ws + 50380800);   // 512*256*2   =    262,144
  float* M = (float*)(ws + 50642944);                        // 768*768*4   =  2,359,296
  float* v = (float*)(ws + 53002240);                        // 768*4       =      3,072
  float* theta = (float*)(ws + 53005312);                    // 2*768*4     =      6,144
  int* idx = (int*)(ws + 53011456);
  float* out_h = (float*)d_out;
  float* out_c = out_h + (size_t)NB * 128;

  hipMemsetAsync(M, 0, 2359296 + 3072, stream);              // zero M and v
  k_prep<<<513, 256, 0, stream>>>(W_ih, W_hh, Wcat, theta);
  k_gates<<<1024, 256, 0, stream>>>(x, h, c, b_ih, Wcat, gvT8, v, out_c);
  k_syrk<<<672, 256, 0, stream>>>(gvT8, M);
  k_symm<<<dim3(3, 768), 256, 0, stream>>>(M);
  for (int s = 0; s < 13; ++s) {
    const float* tin = theta + (s & 1) * 768;
    float* tout = theta + ((s & 1) ^ 1) * 768;
    k_gd<<<768, 64, 0, stream>>>(M, v, tin, tout);
  }
  k_argmax<<<1, 64, 0, stream>>>(theta + 768, idx);          // 13 steps end in buffer 1
  k_gather<<<dim3(1024, 2), 256, 0, stream>>>(gvT8, out_c, idx, out_h);
}